// Round 11
// baseline (856.955 us; speedup 1.0000x reference)
//
#include <hip/hip_runtime.h>

// UniPhyBlock pipeline, round 10: k_moe2 reverted to UNCONSTRAINED launch
// bounds (both occupancy attributes mis-allocate VGPR=64 + spill on this
// toolchain). Keeps ct-phase split (macc[2][16]) + separate bias LDS so the
// allocator can naturally land <=128 VGPR. B=2 T=16 D=64 H=W=64.

#define DEV static __device__ __forceinline__

typedef __attribute__((ext_vector_type(8))) short bf16x8;
typedef __attribute__((ext_vector_type(4))) float f32x4;
typedef __attribute__((ext_vector_type(16))) float f32x16;
typedef __attribute__((ext_vector_type(4))) unsigned int u32x4;

namespace {
constexpr int TN = 32;          // B*T

DEV float sp_f(float x) { return x > 20.f ? x : log1pf(expf(x)); }
DEV unsigned short f2bf(float f) {
  unsigned int u = __float_as_uint(f);
  unsigned int r = (u + 0x7FFFu + ((u >> 16) & 1u)) >> 16;
  return (unsigned short)r;
}
DEV float bf2f(unsigned short s) { return __uint_as_float(((unsigned int)s) << 16); }
DEV unsigned int cvtpk(float lo, float hi) {
  unsigned int u;
  asm("v_cvt_pk_bf16_f32 %0, %1, %2" : "=v"(u) : "v"(lo), "v"(hi));
  return u;
}
// split pair (a,b) into packed bf16 hi word + packed bf16 lo word
DEV void split2(float a, float b, unsigned int& hi, unsigned int& lo) {
  unsigned short ha = f2bf(a), hb = f2bf(b);
  hi = (unsigned int)ha | ((unsigned int)hb << 16);
  float la = a - bf2f(ha), lb = b - bf2f(hb);
  lo = (unsigned int)f2bf(la) | ((unsigned int)f2bf(lb) << 16);
}
DEV float exp2_asm(float x) {
  float r;
  asm("v_exp_f32 %0, %1" : "=v"(r) : "v"(x));  // D = 2^S0
  return r;
}
// fast gelu: x * sigmoid(1.702 x)
DEV float gelu_f(float x) {
  float e = exp2_asm(-2.4554863f * x);
  return x * __builtin_amdgcn_rcpf(1.f + e);
}
} // namespace

// K0c: repack conv_w (Co,Ci,3,3) fp32 -> bf16 MFMA B-fragments
__global__ void k_repc(const float* __restrict__ cw, unsigned short* __restrict__ wcv) {
  int i = blockIdx.x * 256 + threadIdx.x;  // 147456
  if (i >= 9 * 4 * 8 * 64 * 8) return;
  int j = i & 7, l = (i >> 3) & 63, ct = (i >> 9) & 7, cb = (i >> 12) & 3, k = i >> 14;
  int co = ct * 16 + (l & 15);
  int ci = cb * 32 + (l >> 4) * 8 + j;
  wcv[i] = f2bf(cw[((size_t)co * 128 + ci) * 9 + k]);
}

// K0b: repack w1 -> 32x32x16 A-frags, w2 -> 32x32x16 B-frags, rw -> 16x16x32 B-frags
__global__ void k_repw(const float* __restrict__ w1, const float* __restrict__ w2,
                       const float* __restrict__ rw,
                       unsigned short* __restrict__ w1tp, unsigned short* __restrict__ w2p32,
                       unsigned short* __restrict__ rwp) {
  int i = blockIdx.x * 256 + threadIdx.x;
  if (i >= 262144 + 2048) return;
  if (i >= 262144) {
    int idx = i - 262144;
    int j = idx & 7, l = (idx >> 3) & 63, kt = idx >> 9;
    int col = l & 15;
    rwp[idx] = col < 4 ? f2bf(rw[(kt * 32 + (l >> 4) * 8 + j) * 4 + col]) : (unsigned short)0;
    return;
  }
  int half = i >> 17;
  int idx = i & 131071;
  int j = idx & 7, l = (idx >> 3) & 63;
  if (half == 0) {
    int kt = (idx >> 9) & 7, mtG = (idx >> 12) & 7, e = idx >> 15;
    int c = kt * 16 + (l >> 5) * 8 + j, m = mtG * 32 + (l & 31);
    w1tp[idx] = f2bf(w1[((size_t)e * 128 + c) * 256 + m]);
  } else {
    int ct = (idx >> 9) & 3, ktG = (idx >> 11) & 15, e = idx >> 15;
    int m = ktG * 16 + (l >> 5) * 8 + j, c = ct * 32 + (l & 31);
    w2p32[idx] = f2bf(w2[((size_t)e * 256 + m) * 128 + c]);
  }
}

// K0e: prepack E^T, F^T -> 16x16x32 A-fragments, hi then lo halves.
__global__ void k_repEF(const float* __restrict__ Ere, const float* __restrict__ Eim,
                        const float* __restrict__ Fre, const float* __restrict__ Fim,
                        unsigned short* __restrict__ efb) {
  int i = blockIdx.x * 256 + threadIdx.x;
  if (i >= 32768) return;
  int sel = i >> 14;         // 0 = hi, 1 = lo
  int f = i & 16383;
  float val;
  if (f < 8192) {
    int j = f & 7, l = (f >> 3) & 63, kt = (f >> 9) & 1, es = (f >> 10) & 1;
    int v = (f >> 11) & 1, eh = f >> 12;
    int d = kt * 32 + (l >> 4) * 8 + j;
    int e = eh * 32 + es * 16 + (l & 15);
    val = (v ? Eim : Ere)[d * 64 + e];
  } else {
    int g = f - 8192;
    int j = g & 7, l = (g >> 3) & 63, ds = (g >> 9) & 3;
    int v = (g >> 11) & 1, eh = g >> 12;
    int e = eh * 32 + (l >> 4) * 8 + j;
    int d = ds * 16 + (l & 15);
    val = (v ? Fim : Fre)[e * 64 + d];
  }
  unsigned short hv = f2bf(val);
  efb[i] = sel ? f2bf(val - bf2f(hv)) : hv;
}

// K1: layernorm -> xn bf16 [n][p][c]; also raw x -> xfb bf16 [n][p][c]
__global__ __launch_bounds__(256) void k_ln_in(
    const float* __restrict__ xre, const float* __restrict__ xim,
    const float* __restrict__ gg, const float* __restrict__ bb,
    unsigned short* __restrict__ xnb, unsigned short* __restrict__ xfb) {
  int n = blockIdx.x >> 6, h = blockIdx.x & 63;
  __shared__ float xl[64][129];
  __shared__ float ps[4][64], ps2[4][64];
  __shared__ float mu[64], rs[64];
  int tid = threadIdx.x;
  int w = tid & 63, q = tid >> 6;
  size_t base = ((size_t)n * 4096 + h) * 64 + w;
  for (int d = q; d < 64; d += 4) {
    size_t o = base + (size_t)d * 4096;
    xl[w][d] = xre[o];
    xl[w][64 + d] = xim[o];
  }
  __syncthreads();
  float s = 0.f, s2 = 0.f;
  for (int c = q * 32; c < q * 32 + 32; ++c) { float v = xl[w][c]; s += v; s2 += v * v; }
  ps[q][w] = s; ps2[q][w] = s2;
  __syncthreads();
  if (tid < 64) {
    float a = 0.f, b2 = 0.f;
#pragma unroll
    for (int i = 0; i < 4; ++i) { a += ps[i][tid]; b2 += ps2[i][tid]; }
    float m = a * (1.f / 128.f);
    mu[tid] = m;
    rs[tid] = rsqrtf(b2 * (1.f / 128.f) - m * m + 1e-5f);
  }
  __syncthreads();
  size_t obase = ((size_t)n * 4096 + (size_t)h * 64) * 128;
  for (int idx = tid; idx < 64 * 64; idx += 256) {
    int q2 = idx >> 6, c2 = (idx & 63) * 2;
    float r0 = xl[q2][c2], r1 = xl[q2][c2 + 1];
    float v0 = (r0 - mu[q2]) * rs[q2] * gg[c2] + bb[c2];
    float v1 = (r1 - mu[q2]) * rs[q2] * gg[c2 + 1] + bb[c2 + 1];
    *(unsigned int*)&xnb[obase + (size_t)q2 * 128 + c2] = cvtpk(v0, v1);
    *(unsigned int*)&xfb[obase + (size_t)q2 * 128 + c2] = cvtpk(r0, r1);
  }
}

// K2: 3x3 conv via MFMA; epilogue adds xf and emits XS hi/lo B-fragment buffers.
__global__ __launch_bounds__(256) void k_conv(
    const unsigned short* __restrict__ xnb, const unsigned short* __restrict__ wcv,
    const float* __restrict__ cbias, const unsigned short* __restrict__ xfb,
    unsigned short* __restrict__ XSf, unsigned short* __restrict__ XSl) {
  int n = blockIdx.x >> 6, h = blockIdx.x & 63;
  __shared__ __align__(16) short in_t[3 * 66 * 128];
  __shared__ float tr[64][66];
  int tid = threadIdx.x;
  int l = tid & 63;
  int w = __builtin_amdgcn_readfirstlane(tid >> 6);

  for (int it = 0; it < 13; ++it) {
    int ch = tid + it * 256;
    if (ch < 3168) {
      int ri = ch >> 4, cb16 = ch & 15;
      int rr = ri >= 132 ? 2 : (ri >= 66 ? 1 : 0);
      int wp = ri - rr * 66 - 1;
      int hh = h + rr - 1;
      uint4 v = make_uint4(0, 0, 0, 0);
      if ((unsigned)hh < 64u && (unsigned)wp < 64u)
        v = *(const uint4*)(xnb + ((size_t)(n * 4096 + hh * 64 + wp) << 7) + cb16 * 8);
      int off = (ri * 256 + cb16 * 16) ^ ((ri & 7) << 4);
      *(uint4*)((char*)in_t + off) = v;
    }
  }
  __syncthreads();

  f32x4 acc[4][2];
#pragma unroll
  for (int pt = 0; pt < 4; ++pt) { acc[pt][0] = {0,0,0,0}; acc[pt][1] = {0,0,0,0}; }

#pragma unroll
  for (int kh = 0; kh < 3; ++kh) {
#pragma unroll
    for (int kw = 0; kw < 3; ++kw) {
      int k = kh * 3 + kw;
#pragma unroll
      for (int cb = 0; cb < 4; ++cb) {
        const unsigned short* wb = wcv + ((((size_t)(k * 4 + cb) * 8) + 2 * w) * 64 + l) * 8;
        bf16x8 b0 = *(const bf16x8*)wb;
        bf16x8 b1 = *(const bf16x8*)(wb + 64 * 8);
#pragma unroll
        for (int pt = 0; pt < 4; ++pt) {
          int ri = kh * 66 + pt * 16 + (l & 15) + kw;
          int off = (ri * 256 + cb * 64 + (l >> 4) * 16) ^ ((ri & 7) << 4);
          bf16x8 a = *(const bf16x8*)((const char*)in_t + off);
          acc[pt][0] = __builtin_amdgcn_mfma_f32_16x16x32_bf16(a, b0, acc[pt][0], 0, 0, 0);
          acc[pt][1] = __builtin_amdgcn_mfma_f32_16x16x32_bf16(a, b1, acc[pt][1], 0, 0, 0);
        }
      }
    }
  }

  for (int pass = 0; pass < 2; ++pass) {
    __syncthreads();
    if ((w >> 1) == pass) {
      int ctl = w & 1;
#pragma unroll
      for (int ct = 0; ct < 2; ++ct) {
        int col = ctl * 32 + ct * 16 + (l & 15);
        float bias = cbias[pass * 64 + col];
#pragma unroll
        for (int pt = 0; pt < 4; ++pt) {
          int pxb = pt * 16 + (l >> 4) * 4;
          size_t xfo = ((size_t)(n * 4096 + h * 64 + pxb)) * 128 + pass * 64 + col;
#pragma unroll
          for (int r = 0; r < 4; ++r)
            tr[col][pxb + r] = acc[pt][ct][r] + bias + bf2f(xfb[xfo + (size_t)r * 128]);
        }
      }
    }
    __syncthreads();
#pragma unroll
    for (int q = 0; q < 2; ++q) {
      int it = tid + q * 256;
      int ptl = it >> 7, kt = (it >> 6) & 1, lf = it & 63;
      int dbase = kt * 32 + (lf >> 4) * 8;
      int px = ptl * 16 + (lf & 15);
      unsigned int hw[4], lw[4];
#pragma unroll
      for (int u = 0; u < 4; ++u)
        split2(tr[dbase + 2 * u][px], tr[dbase + 2 * u + 1][px], hw[u], lw[u]);
      size_t base = ((((size_t)n * 256 + h * 4 + ptl) * 2 + pass) * 2 + kt) * 512 + lf * 8;
      *(uint4*)(XSf + base) = make_uint4(hw[0], hw[1], hw[2], hw[3]);
      *(uint4*)(XSl + base) = make_uint4(lw[0], lw[1], lw[2], lw[3]);
    }
    __syncthreads();
  }
}

// K3: Xm[n][d] = mean_p XS (hi+lo)
__global__ __launch_bounds__(256) void k_xmean(const unsigned short* __restrict__ XSf,
                                               const unsigned short* __restrict__ XSl,
                                               float2* __restrict__ Xm) {
  int nd = blockIdx.x;
  int n = nd >> 6, d = nd & 63;
  int kt = d >> 5, hs = (d >> 3) & 3, j = d & 7;
  int tid = threadIdx.x;
  float sr = 0.f, si = 0.f;
  for (int p = tid; p < 4096; p += 256) {
    int ptg = p >> 4, c = p & 15;
    size_t b0 = ((((size_t)n * 256 + ptg) * 2 + 0) * 2 + kt) * 512 + (hs * 16 + c) * 8 + j;
    size_t b1 = ((((size_t)n * 256 + ptg) * 2 + 1) * 2 + kt) * 512 + (hs * 16 + c) * 8 + j;
    sr += bf2f(XSf[b0]) + bf2f(XSl[b0]);
    si += bf2f(XSf[b1]) + bf2f(XSl[b1]);
  }
  __shared__ float r1[256], r2[256];
  r1[tid] = sr; r2[tid] = si;
  __syncthreads();
  for (int s = 128; s > 0; s >>= 1) {
    if (tid < s) { r1[tid] += r1[tid + s]; r2[tid] += r2[tid + s]; }
    __syncthreads();
  }
  if (tid == 0) Xm[nd] = make_float2(r1[0] * (1.f / 4096.f), r2[0] * (1.f / 4096.f));
}

// K4: per (b,t): xmean = Xm @ Ec; fcat = [re,im] @ mix_w + mix_b
__global__ void k_chainA(const float2* __restrict__ Xm, const float* __restrict__ Ere,
                         const float* __restrict__ Eim, const float* __restrict__ mixw,
                         const float* __restrict__ mixb, float2* __restrict__ xmix) {
  int n = blockIdx.x;
  int tid = threadIdx.x;  // 128
  __shared__ float2 xm[64];
  __shared__ float cat[128];
  __shared__ float fc[128];
  if (tid < 64) xm[tid] = Xm[n * 64 + tid];
  __syncthreads();
  if (tid < 64) {
    float ar = 0.f, ai = 0.f;
    for (int d = 0; d < 64; ++d) {
      float2 x = xm[d];
      float er = Ere[d * 64 + tid], ei = Eim[d * 64 + tid];
      ar += x.x * er - x.y * ei;
      ai += x.x * ei + x.y * er;
    }
    cat[tid] = ar; cat[64 + tid] = ai;
  }
  __syncthreads();
  {
    float f = mixb[tid];
    for (int i = 0; i < 128; ++i) f += cat[i] * mixw[i * 128 + tid];
    fc[tid] = f;
  }
  __syncthreads();
  if (tid < 64) xmix[n * 64 + tid] = make_float2(fc[tid], fc[64 + tid]);
}

// K5: flux scan over t
__global__ void k_chainB(const float2* __restrict__ xmix, const float* __restrict__ nu,
                         const float* __restrict__ th, const float* __restrict__ fre,
                         const float* __restrict__ fim, float2* __restrict__ fs) {
  int tid = threadIdx.x;  // 128
  int b = tid >> 6, d = tid & 63;
  float r = expf(-sp_f(nu[d]));
  float dr = r * cosf(th[d]), di = r * sinf(th[d]);
  float yr = 0.f, yi = 0.f, cr = 1.f, ci = 0.f;
  float fr = fre[b * 64 + d], fi = fim[b * 64 + d];
  for (int t = 0; t < 16; ++t) {
    int n = b * 16 + t;
    float ncr = cr * dr - ci * di, nci = cr * di + ci * dr;
    cr = ncr; ci = nci;
    float2 xm = xmix[n * 64 + d];
    float nyr = dr * yr - di * yi + xm.x;
    float nyi = dr * yi + di * yr + xm.y;
    yr = nyr; yi = nyi;
    fs[n * 64 + d] = make_float2(yr + fr * cr - fi * ci, yi + fr * ci + fi * cr);
  }
}

// K6: per (b,t): abo[n][e][8] = {a_r, a_i, bb_r, bb_i, od_r, od_i, 0, 0}
__global__ void k_chainC(const float2* __restrict__ fs, const float* __restrict__ srcw,
                         const float* __restrict__ srcb, const float* __restrict__ gw,
                         const float* __restrict__ gbv, const float* __restrict__ la,
                         const float* __restrict__ lbv, const float* __restrict__ dt,
                         float* __restrict__ abo) {
  int n = blockIdx.x;
  int t = n & 15;
  int tid = threadIdx.x;  // 128
  __shared__ float oc[128];
  __shared__ float sl[128];
  if (tid < 64) { float2 v = fs[n * 64 + tid]; oc[tid] = v.x; oc[64 + tid] = v.y; }
  __syncthreads();
  {
    float s = srcb[tid];
    for (int i = 0; i < 128; ++i) s += oc[i] * srcw[i * 128 + tid];
    sl[tid] = s;
  }
  __syncthreads();
  if (tid < 64) {
    float gv = gbv[tid];
    for (int i = 0; i < 128; ++i) gv += oc[i] * gw[i * 64 + tid];
    float g = 1.f / (1.f + expf(-gv));
    float lr = -sp_f(la[tid]), li = lbv[tid];
    float dtv = dt[t];
    float er = expf(lr * dtv);
    float odr = er * cosf(li * dtv), odi = er * sinf(li * dtv);
    float inv = 1.f / (lr * lr + li * li);
    float nx = odr - 1.f, ny = odi;
    float ofr = (nx * lr + ny * li) * inv, ofi = (ny * lr - nx * li) * inv;
    float s1r = sl[tid] * (1.f - g), s1i = sl[64 + tid] * (1.f - g);
    float* ap = abo + ((size_t)n * 64 + tid) * 8;
    ap[0] = g * ofr;
    ap[1] = g * ofi;
    ap[2] = s1r * ofr - s1i * ofi;
    ap[3] = s1r * ofi + s1i * ofr;
    ap[4] = odr;
    ap[5] = odi;
    ap[6] = 0.f; ap[7] = 0.f;
  }
}

// K7 (fused): encode -> forcing -> scan -> decode -> LN -> on. Split-bf16 precision.
__global__ __launch_bounds__(128) void k_state(
    const unsigned short* __restrict__ XSf, const unsigned short* __restrict__ XSl,
    const unsigned short* __restrict__ efb,
    const float* __restrict__ abo, const float* __restrict__ hre,
    const float* __restrict__ him, const float* __restrict__ ntg,
    const float* __restrict__ ntb, unsigned short* __restrict__ onb) {
  int bq = blockIdx.x;
  int b = bq >> 8, pt = bq & 255;
  int p0 = pt * 16;
  int tid = threadIdx.x;
  int l = tid & 63;
  int eh = __builtin_amdgcn_readfirstlane(tid >> 6);
  int c = l & 15, h4 = l >> 4;

  __shared__ float xpart[2 * 64 * 17];
  __shared__ float ntgl[128], ntbl[128];
  ntgl[tid] = ntg[tid]; ntbl[tid] = ntb[tid];

  const unsigned short* Ehi = efb;
  const unsigned short* Fhi = efb + 8192;
  const unsigned short* Elo = efb + 16384;
  const unsigned short* Flo = efb + 24576;

  bf16x8 erh[2][2], eihh[2][2], erl[2][2], eil[2][2];
#pragma unroll
  for (int es = 0; es < 2; ++es)
#pragma unroll
    for (int kt = 0; kt < 2; ++kt) {
      size_t o = (size_t)(eh * 4096 + es * 1024 + kt * 512 + l * 8);
      erh[es][kt] = *(const bf16x8*)(Ehi + o);
      eihh[es][kt] = *(const bf16x8*)(Ehi + o + 2048);
      erl[es][kt] = *(const bf16x8*)(Elo + o);
      eil[es][kt] = *(const bf16x8*)(Elo + o + 2048);
    }
  bf16x8 frh[4], fih[4], frl[4], fil[4];
#pragma unroll
  for (int ds = 0; ds < 4; ++ds) {
    size_t o = (size_t)(eh * 4096 + ds * 512 + l * 8);
    frh[ds] = *(const bf16x8*)(Fhi + o);
    fih[ds] = *(const bf16x8*)(Fhi + o + 2048);
    frl[ds] = *(const bf16x8*)(Flo + o);
    fil[ds] = *(const bf16x8*)(Flo + o + 2048);
  }

  float yre[2][4], yim[2][4];
#pragma unroll
  for (int es = 0; es < 2; ++es)
#pragma unroll
    for (int r = 0; r < 4; ++r) { yre[es][r] = 0.f; yim[es][r] = 0.f; }

  __syncthreads();

  const f32x4 Z = {0.f, 0.f, 0.f, 0.f};
  for (int t = 0; t < 16; ++t) {
    int n = b * 16 + t;
    bf16x8 xh0[2], xh1[2], xq0[2], xq1[2];
#pragma unroll
    for (int kt = 0; kt < 2; ++kt) {
      size_t b0 = ((((size_t)n * 256 + pt) * 2 + 0) * 2 + kt) * 512 + l * 8;
      size_t b1 = ((((size_t)n * 256 + pt) * 2 + 1) * 2 + kt) * 512 + l * 8;
      xh0[kt] = *(const bf16x8*)(XSf + b0);
      xh1[kt] = *(const bf16x8*)(XSf + b1);
      xq0[kt] = *(const bf16x8*)(XSl + b0);
      xq1[kt] = *(const bf16x8*)(XSl + b1);
    }
    // ---- encode (triple product) + forcing + scan
#pragma unroll
    for (int es = 0; es < 2; ++es) {
      f32x4 a1 = Z, a2 = Z, a3 = Z, a4 = Z;
#pragma unroll
      for (int kt = 0; kt < 2; ++kt) {
        a1 = __builtin_amdgcn_mfma_f32_16x16x32_bf16(erh[es][kt], xh0[kt], a1, 0, 0, 0);
        a1 = __builtin_amdgcn_mfma_f32_16x16x32_bf16(erh[es][kt], xq0[kt], a1, 0, 0, 0);
        a1 = __builtin_amdgcn_mfma_f32_16x16x32_bf16(erl[es][kt], xh0[kt], a1, 0, 0, 0);
        a2 = __builtin_amdgcn_mfma_f32_16x16x32_bf16(eihh[es][kt], xh1[kt], a2, 0, 0, 0);
        a2 = __builtin_amdgcn_mfma_f32_16x16x32_bf16(eihh[es][kt], xq1[kt], a2, 0, 0, 0);
        a2 = __builtin_amdgcn_mfma_f32_16x16x32_bf16(eil[es][kt], xh1[kt], a2, 0, 0, 0);
        a3 = __builtin_amdgcn_mfma_f32_16x16x32_bf16(eihh[es][kt], xh0[kt], a3, 0, 0, 0);
        a3 = __builtin_amdgcn_mfma_f32_16x16x32_bf16(eihh[es][kt], xq0[kt], a3, 0, 0, 0);
        a3 = __builtin_amdgcn_mfma_f32_16x16x32_bf16(eil[es][kt], xh0[kt], a3, 0, 0, 0);
        a4 = __builtin_amdgcn_mfma_f32_16x16x32_bf16(erh[es][kt], xh1[kt], a4, 0, 0, 0);
        a4 = __builtin_amdgcn_mfma_f32_16x16x32_bf16(erh[es][kt], xq1[kt], a4, 0, 0, 0);
        a4 = __builtin_amdgcn_mfma_f32_16x16x32_bf16(erl[es][kt], xh1[kt], a4, 0, 0, 0);
      }
#pragma unroll
      for (int r = 0; r < 4; ++r) {
        int e = eh * 32 + es * 16 + 4 * h4 + r;
        const float* ap = abo + ((size_t)n * 64 + e) * 8;
        float4 cv = *(const float4*)ap;
        float2 ov = *(const float2*)(ap + 4);
        float xr_ = a1[r] - a2[r], xi_ = a3[r] + a4[r];
        float ur = xr_ * cv.x - xi_ * cv.y + cv.z;
        float ui = xr_ * cv.y + xi_ * cv.x + cv.w;
        if (t == 0) {
          size_t ho = ((size_t)(b * 4096 + p0 + c)) * 64 + e;
          float hr = hre[ho], hi = him[ho];
          ur += hr * ov.x - hi * ov.y;
          ui += hr * ov.y + hi * ov.x;
        }
        float nyr = ov.x * yre[es][r] - ov.y * yim[es][r] + ur;
        float nyi = ov.x * yim[es][r] + ov.y * yre[es][r] + ui;
        yre[es][r] = nyr; yim[es][r] = nyi;
      }
    }
    // ---- y -> split bf16 hi/lo B-fragments, in-register shfl transpose.
    unsigned int hr_[2][2], lr_[2][2], hi_[2][2], li_[2][2];
#pragma unroll
    for (int es = 0; es < 2; ++es) {
      split2(yre[es][0], yre[es][1], hr_[es][0], lr_[es][0]);
      split2(yre[es][2], yre[es][3], hr_[es][1], lr_[es][1]);
      split2(yim[es][0], yim[es][1], hi_[es][0], li_[es][0]);
      split2(yim[es][2], yim[es][3], hi_[es][1], li_[es][1]);
    }
    int base_src = c + 16 * (2 * (h4 & 1));
    int hsel = h4 >> 1;
    u32x4 urh, uih, url, uil;
#pragma unroll
    for (int jj = 0; jj < 4; ++jj) {
      int src = base_src + 16 * (jj >> 1);
      unsigned int t0, t1;
      t0 = (unsigned int)__shfl((int)hr_[0][jj & 1], src);
      t1 = (unsigned int)__shfl((int)hr_[1][jj & 1], src);
      urh[jj] = hsel ? t1 : t0;
      t0 = (unsigned int)__shfl((int)hi_[0][jj & 1], src);
      t1 = (unsigned int)__shfl((int)hi_[1][jj & 1], src);
      uih[jj] = hsel ? t1 : t0;
      t0 = (unsigned int)__shfl((int)lr_[0][jj & 1], src);
      t1 = (unsigned int)__shfl((int)lr_[1][jj & 1], src);
      url[jj] = hsel ? t1 : t0;
      t0 = (unsigned int)__shfl((int)li_[0][jj & 1], src);
      t1 = (unsigned int)__shfl((int)li_[1][jj & 1], src);
      uil[jj] = hsel ? t1 : t0;
    }
    bf16x8 ybrh = __builtin_bit_cast(bf16x8, urh);
    bf16x8 ybih = __builtin_bit_cast(bf16x8, uih);
    bf16x8 ybrl = __builtin_bit_cast(bf16x8, url);
    bf16x8 ybil = __builtin_bit_cast(bf16x8, uil);
    // ---- decode (triple product, partial over this wave's e-half)
    float v[2][4][4];
#pragma unroll
    for (int ds = 0; ds < 4; ++ds) {
      f32x4 d1 = Z, d2 = Z, d3 = Z, d4 = Z;
      d1 = __builtin_amdgcn_mfma_f32_16x16x32_bf16(frh[ds], ybrh, d1, 0, 0, 0);
      d1 = __builtin_amdgcn_mfma_f32_16x16x32_bf16(frh[ds], ybrl, d1, 0, 0, 0);
      d1 = __builtin_amdgcn_mfma_f32_16x16x32_bf16(frl[ds], ybrh, d1, 0, 0, 0);
      d2 = __builtin_amdgcn_mfma_f32_16x16x32_bf16(fih[ds], ybih, d2, 0, 0, 0);
      d2 = __builtin_amdgcn_mfma_f32_16x16x32_bf16(fih[ds], ybil, d2, 0, 0, 0);
      d2 = __builtin_amdgcn_mfma_f32_16x16x32_bf16(fil[ds], ybih, d2, 0, 0, 0);
      d3 = __builtin_amdgcn_mfma_f32_16x16x32_bf16(fih[ds], ybrh, d3, 0, 0, 0);
      d3 = __builtin_amdgcn_mfma_f32_16x16x32_bf16(fih[ds], ybrl, d3, 0, 0, 0);
      d3 = __builtin_amdgcn_mfma_f32_16x16x32_bf16(fil[ds], ybrh, d3, 0, 0, 0);
      d4 = __builtin_amdgcn_mfma_f32_16x16x32_bf16(frh[ds], ybih, d4, 0, 0, 0);
      d4 = __builtin_amdgcn_mfma_f32_16x16x32_bf16(frh[ds], ybil, d4, 0, 0, 0);
      d4 = __builtin_amdgcn_mfma_f32_16x16x32_bf16(frl[ds], ybih, d4, 0, 0, 0);
#pragma unroll
      for (int r = 0; r < 4; ++r) {
        v[0][ds][r] = d1[r] - d2[r];
        v[1][ds][r] = d3[r] + d4[r];
      }
    }
    bool own = (eh == (t & 1));
    if (!own) {
#pragma unroll
      for (int p = 0; p < 2; ++p)
#pragma unroll
        for (int ds = 0; ds < 4; ++ds)
#pragma unroll
          for (int r = 0; r < 4; ++r)
            xpart[(p * 64 + ds * 16 + 4 * h4 + r) * 17 + c] = v[p][ds][r];
    }
    __syncthreads();
    if (own) {
      float s = 0.f, s2 = 0.f;
#pragma unroll
      for (int p = 0; p < 2; ++p)
#pragma unroll
        for (int ds = 0; ds < 4; ++ds)
#pragma unroll
          for (int r = 0; r < 4; ++r) {
            float q2 = v[p][ds][r] + xpart[(p * 64 + ds * 16 + 4 * h4 + r) * 17 + c];
            v[p][ds][r] = q2;
            s += q2; s2 += q2 * q2;
          }
      s += __shfl_xor(s, 16); s += __shfl_xor(s, 32);
      s2 += __shfl_xor(s2, 16); s2 += __shfl_xor(s2, 32);
      float mu = s * (1.f / 128.f);
      float rsv = rsqrtf(s2 * (1.f / 128.f) - mu * mu + 1e-5f);
      size_t ob = ((size_t)(n * 4096 + p0 + c)) * 128;
#pragma unroll
      for (int p = 0; p < 2; ++p)
#pragma unroll
        for (int ds = 0; ds < 4; ++ds) {
          int ch = p * 64 + ds * 16 + 4 * h4;
          float l0 = (v[p][ds][0] - mu) * rsv * ntgl[ch + 0] + ntbl[ch + 0];
          float l1 = (v[p][ds][1] - mu) * rsv * ntgl[ch + 1] + ntbl[ch + 1];
          float l2 = (v[p][ds][2] - mu) * rsv * ntgl[ch + 2] + ntbl[ch + 2];
          float l3 = (v[p][ds][3] - mu) * rsv * ntgl[ch + 3] + ntbl[ch + 3];
          *(unsigned int*)&onb[ob + ch] = cvtpk(l0, l1);
          *(unsigned int*)&onb[ob + ch + 2] = cvtpk(l2, l3);
        }
    }
    __syncthreads();
  }
}

// K10: MoE via swapped-operand 32x32 MFMA; residual from XS hi+lo.
// ct-phase split: macc[2][16]; separate bias LDS; NO occupancy attributes.
__global__ __launch_bounds__(256) void k_moe2(
    const unsigned short* __restrict__ onb, const unsigned short* __restrict__ w1tp,
    const unsigned short* __restrict__ w2p32, const unsigned short* __restrict__ rwp,
    const float* __restrict__ rb, const float* __restrict__ b1, const float* __restrict__ b2,
    const unsigned short* __restrict__ XSf, const unsigned short* __restrict__ XSl,
    float* __restrict__ out) {
  int n = blockIdx.x >> 6, ptile = blockIdx.x & 63;
  int p0 = ptile * 64;
  __shared__ __align__(16) short At[64 * 128];   // 16384 B
  __shared__ __align__(16) float buf[4160];      // 16640 B: red / fin
  __shared__ float pr[64][4];                    // 1024 B
  __shared__ float b1l[1024];                    // 4096 B
  __shared__ float b2l[512];                     // 2048 B  (total 40192 B)
  int tid = threadIdx.x;
  int l = tid & 63;
  int w = __builtin_amdgcn_readfirstlane(tid >> 6);
  int h = l >> 5, s = l & 31;

  for (int i = tid; i < 1024; i += 256) b1l[i] = b1[i];
  for (int i = tid; i < 512; i += 256) b2l[i] = b2[i];

  {
    const char* gsrc = (const char*)onb + ((size_t)n * 4096 + p0) * 256;
#pragma unroll
    for (int it = 0; it < 4; ++it) {
      int ch = tid + it * 256;
      int row = ch >> 4, cb = (ch & 15) * 16;
      float4 v = *(const float4*)(gsrc + (size_t)row * 256 + cb);
      int off = (row * 256 + cb) ^ ((row & 7) << 4);
      *(float4*)((char*)At + off) = v;
    }
  }
  __syncthreads();

  {
    f32x4 acc = {0.f, 0.f, 0.f, 0.f};
#pragma unroll
    for (int kt = 0; kt < 4; ++kt) {
      int row = w * 16 + (l & 15);
      int off = (row * 256 + kt * 64 + (l >> 4) * 16) ^ ((row & 7) << 4);
      bf16x8 aa = *(const bf16x8*)((const char*)At + off);
      bf16x8 bb = *(const bf16x8*)(rwp + ((size_t)kt * 64 + l) * 8);
      acc = __builtin_amdgcn_mfma_f32_16x16x32_bf16(aa, bb, acc, 0, 0, 0);
    }
    int e = l & 15;
    float rbv = e < 4 ? rb[e] : 0.f;
#pragma unroll
    for (int r = 0; r < 4; ++r) {
      float lg = acc[r] + rbv;
      float m = fmaxf(lg, __shfl_xor(lg, 1));
      m = fmaxf(m, __shfl_xor(m, 2));
      float ex = __expf(lg - m);
      float sm = ex + __shfl_xor(ex, 1);
      sm += __shfl_xor(sm, 2);
      float p = ex * __builtin_amdgcn_rcpf(sm);
      if (e < 4) pr[w * 16 + (l >> 4) * 4 + r][e] = p;
    }
  }

  int pw = w & 1, mh = w >> 1;
  int rowb = pw * 32 + s;
  int swz = (rowb & 7) << 4;
  const f32x16 Z16 = {0.f, 0.f, 0.f, 0.f, 0.f, 0.f, 0.f, 0.f,
                      0.f, 0.f, 0.f, 0.f, 0.f, 0.f, 0.f, 0.f};

  for (int ph = 0; ph < 2; ++ph) {
    __syncthreads();   // pr ready (ph=0) / buf free from prior phase (ph=1)
    float macc[2][16];
#pragma unroll
    for (int cti = 0; cti < 2; ++cti)
#pragma unroll
      for (int r = 0; r < 16; ++r) macc[cti][r] = 0.f;

    for (int e = 0; e < 4; ++e) {
      u32x4 af[8];
#pragma unroll
      for (int mt = 0; mt < 4; ++mt) {
        f32x16 acc = Z16;
#pragma unroll
        for (int kt = 0; kt < 8; ++kt) {
          bf16x8 a = *(const bf16x8*)(
              w1tp + ((((size_t)e * 8 + (mh * 4 + mt)) * 8 + kt) * 64 + l) * 8);
          int off = (rowb * 256 + kt * 32 + h * 16) ^ swz;
          bf16x8 b = *(const bf16x8*)((const char*)At + off);
          acc = __builtin_amdgcn_mfma_f32_32x32x16_bf16(a, b, acc, 0, 0, 0);
        }
        unsigned int hpk[8];
#pragma unroll
        for (int i2 = 0; i2 < 8; ++i2) {
          int r0 = 2 * i2;
          int m0 = mh * 128 + mt * 32 + (r0 & 3) + 8 * (r0 >> 2) + 4 * h;
          float2 bv = *(const float2*)&b1l[e * 256 + m0];
          hpk[i2] = cvtpk(gelu_f(acc[r0] + bv.x), gelu_f(acc[r0 + 1] + bv.y));
        }
#pragma unroll
        for (int hf = 0; hf < 2; ++hf) {
          unsigned int pA = hpk[4 * hf + 0], pB = hpk[4 * hf + 1];
          unsigned int pC = hpk[4 * hf + 2], pD = hpk[4 * hf + 3];
          unsigned int Z0 = h ? pC : pA, Z1 = h ? pD : pB;
          unsigned int S0 = h ? pA : pC, S1 = h ? pB : pD;
          unsigned int Ss0 = (unsigned int)__shfl_xor((int)S0, 32);
          unsigned int Ss1 = (unsigned int)__shfl_xor((int)S1, 32);
          u32x4 fr2;
          fr2.x = h ? Ss0 : Z0;
          fr2.y = h ? Ss1 : Z1;
          fr2.z = h ? Z0 : Ss0;
          fr2.w = h ? Z1 : Ss1;
          af[mt * 2 + hf] = fr2;
        }
      }
      float prv[16];
#pragma unroll
      for (int r = 0; r < 16; ++r) {
        int px = pw * 32 + (r & 3) + 8 * (r >> 2) + 4 * h;
        prv[r] = pr[px][e];
      }
#pragma unroll
      for (int cti = 0; cti < 2; ++cti) {
        int ct = ph * 2 + cti;
        f32x16 acc = Z16;
#pragma unroll
        for (int kt = 0; kt < 8; ++kt) {
          bf16x8 bf = *(const bf16x8*)(
              w2p32 + ((((size_t)e * 16 + (mh * 8 + kt)) * 4 + ct) * 64 + l) * 8);
          bf16x8 a = __builtin_bit_cast(bf16x8, af[kt]);
          acc = __builtin_amdgcn_mfma_f32_32x32x16_bf16(a, bf, acc, 0, 0, 0);
        }
        float b2v = mh ? 0.f : b2l[e * 128 + ct * 32 + s];
#pragma unroll
        for (int r = 0; r < 16; ++r) macc[cti][r] += (acc[r] + b2v) * prv[r];
      }
    }

    // reduce over mh, fin, out-write for this ct-pair (64 channels)
    __syncthreads();
    if (mh == 1) {
#pragma unroll
      for (int g = 0; g < 8; ++g) {
        int cti = g >> 2, q = (g & 3) * 4;
        float4 v = make_float4(macc[cti][q], macc[cti][q + 1], macc[cti][q + 2],
                               macc[cti][q + 3]);
        *(float4*)&buf[((g * 2 + pw) * 64 + l) * 4] = v;
      }
    }
    __syncthreads();
    if (mh == 0) {
#pragma unroll
      for (int g = 0; g < 8; ++g) {
        float4 v = *(const float4*)&buf[((g * 2 + pw) * 64 + l) * 4];
        int cti = g >> 2, q = (g & 3) * 4;
        macc[cti][q] += v.x; macc[cti][q + 1] += v.y;
        macc[cti][q + 2] += v.z; macc[cti][q + 3] += v.w;
      }
    }
    __syncthreads();
    if (mh == 0) {
#pragma unroll
      for (int cti = 0; cti < 2; ++cti) {
        int ct = ph * 2 + cti;
        int cc = ct * 32 + s;
        int cl = cc - ph * 64;
#pragma unroll
        for (int r = 0; r < 16; ++r) {
          int px = pw * 32 + (r & 3) + 8 * (r >> 2) + 4 * h;
          int aoff = (px * 256 + cc * 2) ^ ((px & 7) << 4);
          float onv = bf2f(((unsigned short*)At)[aoff >> 1]);
          buf[px * 65 + cl] = macc[cti][r] + onv;
        }
      }
    }
    __syncthreads();
    for (int idx = tid; idx < 64 * 64; idx += 256) {
      int px = idx & 63, cl = idx >> 6;
      int p = p0 + px;
      size_t el = ((((size_t)n * 256 + (p >> 4)) * 2 + ph) * 2 + (cl >> 5)) * 512
                + (((cl >> 3) & 3) * 16 + (p & 15)) * 8 + (cl & 7);
      float resid = bf2f(XSf[el]) + bf2f(XSl[el]);
      out[((size_t)n * 128 + ph * 64 + cl) * 4096 + p0 + px] = resid + buf[px * 65 + cl];
    }
  }
}

extern "C" void kernel_launch(void* const* d_in, const int* in_sizes, int n_in,
                              void* d_out, int out_size, void* d_ws, size_t ws_size,
                              hipStream_t stream) {
  const float* xre = (const float*)d_in[0];
  const float* xim = (const float*)d_in[1];
  const float* hre = (const float*)d_in[2];
  const float* him = (const float*)d_in[3];
  const float* dt = (const float*)d_in[4];
  const float* fre = (const float*)d_in[5];
  const float* fim = (const float*)d_in[6];
  const float* nsg = (const float*)d_in[7];
  const float* nsb = (const float*)d_in[8];
  const float* cw = (const float*)d_in[9];
  const float* cb = (const float*)d_in[10];
  const float* Ere = (const float*)d_in[11];
  const float* Eim = (const float*)d_in[12];
  const float* Fre = (const float*)d_in[13];
  const float* Fim = (const float*)d_in[14];
  const float* mixw = (const float*)d_in[15];
  const float* mixb = (const float*)d_in[16];
  const float* nu = (const float*)d_in[17];
  const float* th = (const float*)d_in[18];
  const float* srcw = (const float*)d_in[19];
  const float* srcb = (const float*)d_in[20];
  const float* gw = (const float*)d_in[21];
  const float* gbv = (const float*)d_in[22];
  const float* la = (const float*)d_in[23];
  const float* lb = (const float*)d_in[24];
  const float* ntg = (const float*)d_in[25];
  const float* ntb = (const float*)d_in[26];
  const float* rw = (const float*)d_in[27];
  const float* rb = (const float*)d_in[28];
  const float* w1 = (const float*)d_in[29];
  const float* b1 = (const float*)d_in[30];
  const float* w2 = (const float*)d_in[31];
  const float* b2 = (const float*)d_in[32];

  unsigned short* XSf = (unsigned short*)d_ws;
  unsigned short* XSl = XSf + 16777216;
  unsigned short* onb16 = XSl + 16777216;
  unsigned short* wcv = onb16 + 16777216;        // 147456
  unsigned short* w1tp = wcv + 147456;           // 131072
  unsigned short* w2p32 = w1tp + 131072;         // 131072
  unsigned short* rwp = w2p32 + 131072;          // 2048
  unsigned short* efb = rwp + 2048;              // 32768 (hi 16384 + lo 16384)
  float* smf = (float*)(efb + 32768);
  float* abo = smf;                              // 32*64*8 = 16384 f32
  float2* Xm = (float2*)(abo + 16384);           // 2048 float2
  float2* xmix = Xm + TN * 64;
  float2* fsb = xmix + TN * 64;

  float* out = (float*)d_out;
  unsigned short* xnb = (unsigned short*)d_out;        // bf16, dead after k_conv
  unsigned short* xfb = xnb + 16777216;                // bf16 raw x, dead after k_conv

  hipLaunchKernelGGL(k_repc, dim3(576), dim3(256), 0, stream, cw, wcv);
  hipLaunchKernelGGL(k_repw, dim3(1033), dim3(256), 0, stream, w1, w2, rw, w1tp, w2p32, rwp);
  hipLaunchKernelGGL(k_repEF, dim3(128), dim3(256), 0, stream, Ere, Eim, Fre, Fim, efb);
  hipLaunchKernelGGL(k_ln_in, dim3(TN * 64), dim3(256), 0, stream, xre, xim, nsg, nsb, xnb, xfb);
  hipLaunchKernelGGL(k_conv, dim3(TN * 64), dim3(256), 0, stream, xnb, wcv, cb, xfb, XSf, XSl);
  hipLaunchKernelGGL(k_xmean, dim3(TN * 64), dim3(256), 0, stream, XSf, XSl, Xm);
  hipLaunchKernelGGL(k_chainA, dim3(TN), dim3(128), 0, stream, Xm, Ere, Eim, mixw, mixb, xmix);
  hipLaunchKernelGGL(k_chainB, dim3(1), dim3(128), 0, stream, xmix, nu, th, fre, fim, fsb);
  hipLaunchKernelGGL(k_chainC, dim3(TN), dim3(128), 0, stream, fsb, srcw, srcb, gw, gbv, la, lb,
                     dt, abo);
  hipLaunchKernelGGL(k_state, dim3(512), dim3(128), 0, stream, XSf, XSl, efb, abo, hre, him,
                     ntg, ntb, onb16);
  hipLaunchKernelGGL(k_moe2, dim3(TN * 64), dim3(256), 0, stream, onb16, w1tp, w2p32, rwp, rb,
                     b1, b2, XSf, XSl, out);
  (void)in_sizes; (void)n_in; (void)out_size; (void)ws_size;
}

// Round 12
// 500.019 us; speedup vs baseline: 1.7138x; 1.7138x over previous
//
#include <hip/hip_runtime.h>

// UniPhyBlock pipeline, round 11: k_moe2 = single e-loop (macc[4][16], the
// 248us-proven structure) + 2-phase epilogue (LDS 34304) + NO occupancy
// attributes (both attributes force VGPR=64 + spill on this toolchain).
// B=2 T=16 D=64 H=W=64.

#define DEV static __device__ __forceinline__

typedef __attribute__((ext_vector_type(8))) short bf16x8;
typedef __attribute__((ext_vector_type(4))) float f32x4;
typedef __attribute__((ext_vector_type(16))) float f32x16;
typedef __attribute__((ext_vector_type(4))) unsigned int u32x4;

namespace {
constexpr int TN = 32;          // B*T

DEV float sp_f(float x) { return x > 20.f ? x : log1pf(expf(x)); }
DEV unsigned short f2bf(float f) {
  unsigned int u = __float_as_uint(f);
  unsigned int r = (u + 0x7FFFu + ((u >> 16) & 1u)) >> 16;
  return (unsigned short)r;
}
DEV float bf2f(unsigned short s) { return __uint_as_float(((unsigned int)s) << 16); }
DEV unsigned int cvtpk(float lo, float hi) {
  unsigned int u;
  asm("v_cvt_pk_bf16_f32 %0, %1, %2" : "=v"(u) : "v"(lo), "v"(hi));
  return u;
}
// split pair (a,b) into packed bf16 hi word + packed bf16 lo word
DEV void split2(float a, float b, unsigned int& hi, unsigned int& lo) {
  unsigned short ha = f2bf(a), hb = f2bf(b);
  hi = (unsigned int)ha | ((unsigned int)hb << 16);
  float la = a - bf2f(ha), lb = b - bf2f(hb);
  lo = (unsigned int)f2bf(la) | ((unsigned int)f2bf(lb) << 16);
}
DEV float exp2_asm(float x) {
  float r;
  asm("v_exp_f32 %0, %1" : "=v"(r) : "v"(x));  // D = 2^S0
  return r;
}
// fast gelu: x * sigmoid(1.702 x)
DEV float gelu_f(float x) {
  float e = exp2_asm(-2.4554863f * x);
  return x * __builtin_amdgcn_rcpf(1.f + e);
}
} // namespace

// K0c: repack conv_w (Co,Ci,3,3) fp32 -> bf16 MFMA B-fragments
__global__ void k_repc(const float* __restrict__ cw, unsigned short* __restrict__ wcv) {
  int i = blockIdx.x * 256 + threadIdx.x;  // 147456
  if (i >= 9 * 4 * 8 * 64 * 8) return;
  int j = i & 7, l = (i >> 3) & 63, ct = (i >> 9) & 7, cb = (i >> 12) & 3, k = i >> 14;
  int co = ct * 16 + (l & 15);
  int ci = cb * 32 + (l >> 4) * 8 + j;
  wcv[i] = f2bf(cw[((size_t)co * 128 + ci) * 9 + k]);
}

// K0b: repack w1 -> 32x32x16 A-frags, w2 -> 32x32x16 B-frags, rw -> 16x16x32 B-frags
__global__ void k_repw(const float* __restrict__ w1, const float* __restrict__ w2,
                       const float* __restrict__ rw,
                       unsigned short* __restrict__ w1tp, unsigned short* __restrict__ w2p32,
                       unsigned short* __restrict__ rwp) {
  int i = blockIdx.x * 256 + threadIdx.x;
  if (i >= 262144 + 2048) return;
  if (i >= 262144) {
    int idx = i - 262144;
    int j = idx & 7, l = (idx >> 3) & 63, kt = idx >> 9;
    int col = l & 15;
    rwp[idx] = col < 4 ? f2bf(rw[(kt * 32 + (l >> 4) * 8 + j) * 4 + col]) : (unsigned short)0;
    return;
  }
  int half = i >> 17;
  int idx = i & 131071;
  int j = idx & 7, l = (idx >> 3) & 63;
  if (half == 0) {
    int kt = (idx >> 9) & 7, mtG = (idx >> 12) & 7, e = idx >> 15;
    int c = kt * 16 + (l >> 5) * 8 + j, m = mtG * 32 + (l & 31);
    w1tp[idx] = f2bf(w1[((size_t)e * 128 + c) * 256 + m]);
  } else {
    int ct = (idx >> 9) & 3, ktG = (idx >> 11) & 15, e = idx >> 15;
    int m = ktG * 16 + (l >> 5) * 8 + j, c = ct * 32 + (l & 31);
    w2p32[idx] = f2bf(w2[((size_t)e * 256 + m) * 128 + c]);
  }
}

// K0e: prepack E^T, F^T -> 16x16x32 A-fragments, hi then lo halves.
__global__ void k_repEF(const float* __restrict__ Ere, const float* __restrict__ Eim,
                        const float* __restrict__ Fre, const float* __restrict__ Fim,
                        unsigned short* __restrict__ efb) {
  int i = blockIdx.x * 256 + threadIdx.x;
  if (i >= 32768) return;
  int sel = i >> 14;         // 0 = hi, 1 = lo
  int f = i & 16383;
  float val;
  if (f < 8192) {
    int j = f & 7, l = (f >> 3) & 63, kt = (f >> 9) & 1, es = (f >> 10) & 1;
    int v = (f >> 11) & 1, eh = f >> 12;
    int d = kt * 32 + (l >> 4) * 8 + j;
    int e = eh * 32 + es * 16 + (l & 15);
    val = (v ? Eim : Ere)[d * 64 + e];
  } else {
    int g = f - 8192;
    int j = g & 7, l = (g >> 3) & 63, ds = (g >> 9) & 3;
    int v = (g >> 11) & 1, eh = g >> 12;
    int e = eh * 32 + (l >> 4) * 8 + j;
    int d = ds * 16 + (l & 15);
    val = (v ? Fim : Fre)[e * 64 + d];
  }
  unsigned short hv = f2bf(val);
  efb[i] = sel ? f2bf(val - bf2f(hv)) : hv;
}

// K1: layernorm -> xn bf16 [n][p][c]; also raw x -> xfb bf16 [n][p][c]
__global__ __launch_bounds__(256) void k_ln_in(
    const float* __restrict__ xre, const float* __restrict__ xim,
    const float* __restrict__ gg, const float* __restrict__ bb,
    unsigned short* __restrict__ xnb, unsigned short* __restrict__ xfb) {
  int n = blockIdx.x >> 6, h = blockIdx.x & 63;
  __shared__ float xl[64][129];
  __shared__ float ps[4][64], ps2[4][64];
  __shared__ float mu[64], rs[64];
  int tid = threadIdx.x;
  int w = tid & 63, q = tid >> 6;
  size_t base = ((size_t)n * 4096 + h) * 64 + w;
  for (int d = q; d < 64; d += 4) {
    size_t o = base + (size_t)d * 4096;
    xl[w][d] = xre[o];
    xl[w][64 + d] = xim[o];
  }
  __syncthreads();
  float s = 0.f, s2 = 0.f;
  for (int c = q * 32; c < q * 32 + 32; ++c) { float v = xl[w][c]; s += v; s2 += v * v; }
  ps[q][w] = s; ps2[q][w] = s2;
  __syncthreads();
  if (tid < 64) {
    float a = 0.f, b2 = 0.f;
#pragma unroll
    for (int i = 0; i < 4; ++i) { a += ps[i][tid]; b2 += ps2[i][tid]; }
    float m = a * (1.f / 128.f);
    mu[tid] = m;
    rs[tid] = rsqrtf(b2 * (1.f / 128.f) - m * m + 1e-5f);
  }
  __syncthreads();
  size_t obase = ((size_t)n * 4096 + (size_t)h * 64) * 128;
  for (int idx = tid; idx < 64 * 64; idx += 256) {
    int q2 = idx >> 6, c2 = (idx & 63) * 2;
    float r0 = xl[q2][c2], r1 = xl[q2][c2 + 1];
    float v0 = (r0 - mu[q2]) * rs[q2] * gg[c2] + bb[c2];
    float v1 = (r1 - mu[q2]) * rs[q2] * gg[c2 + 1] + bb[c2 + 1];
    *(unsigned int*)&xnb[obase + (size_t)q2 * 128 + c2] = cvtpk(v0, v1);
    *(unsigned int*)&xfb[obase + (size_t)q2 * 128 + c2] = cvtpk(r0, r1);
  }
}

// K2: 3x3 conv via MFMA; epilogue adds xf and emits XS hi/lo B-fragment buffers.
__global__ __launch_bounds__(256) void k_conv(
    const unsigned short* __restrict__ xnb, const unsigned short* __restrict__ wcv,
    const float* __restrict__ cbias, const unsigned short* __restrict__ xfb,
    unsigned short* __restrict__ XSf, unsigned short* __restrict__ XSl) {
  int n = blockIdx.x >> 6, h = blockIdx.x & 63;
  __shared__ __align__(16) short in_t[3 * 66 * 128];
  __shared__ float tr[64][66];
  int tid = threadIdx.x;
  int l = tid & 63;
  int w = __builtin_amdgcn_readfirstlane(tid >> 6);

  for (int it = 0; it < 13; ++it) {
    int ch = tid + it * 256;
    if (ch < 3168) {
      int ri = ch >> 4, cb16 = ch & 15;
      int rr = ri >= 132 ? 2 : (ri >= 66 ? 1 : 0);
      int wp = ri - rr * 66 - 1;
      int hh = h + rr - 1;
      uint4 v = make_uint4(0, 0, 0, 0);
      if ((unsigned)hh < 64u && (unsigned)wp < 64u)
        v = *(const uint4*)(xnb + ((size_t)(n * 4096 + hh * 64 + wp) << 7) + cb16 * 8);
      int off = (ri * 256 + cb16 * 16) ^ ((ri & 7) << 4);
      *(uint4*)((char*)in_t + off) = v;
    }
  }
  __syncthreads();

  f32x4 acc[4][2];
#pragma unroll
  for (int pt = 0; pt < 4; ++pt) { acc[pt][0] = {0,0,0,0}; acc[pt][1] = {0,0,0,0}; }

#pragma unroll
  for (int kh = 0; kh < 3; ++kh) {
#pragma unroll
    for (int kw = 0; kw < 3; ++kw) {
      int k = kh * 3 + kw;
#pragma unroll
      for (int cb = 0; cb < 4; ++cb) {
        const unsigned short* wb = wcv + ((((size_t)(k * 4 + cb) * 8) + 2 * w) * 64 + l) * 8;
        bf16x8 b0 = *(const bf16x8*)wb;
        bf16x8 b1 = *(const bf16x8*)(wb + 64 * 8);
#pragma unroll
        for (int pt = 0; pt < 4; ++pt) {
          int ri = kh * 66 + pt * 16 + (l & 15) + kw;
          int off = (ri * 256 + cb * 64 + (l >> 4) * 16) ^ ((ri & 7) << 4);
          bf16x8 a = *(const bf16x8*)((const char*)in_t + off);
          acc[pt][0] = __builtin_amdgcn_mfma_f32_16x16x32_bf16(a, b0, acc[pt][0], 0, 0, 0);
          acc[pt][1] = __builtin_amdgcn_mfma_f32_16x16x32_bf16(a, b1, acc[pt][1], 0, 0, 0);
        }
      }
    }
  }

  for (int pass = 0; pass < 2; ++pass) {
    __syncthreads();
    if ((w >> 1) == pass) {
      int ctl = w & 1;
#pragma unroll
      for (int ct = 0; ct < 2; ++ct) {
        int col = ctl * 32 + ct * 16 + (l & 15);
        float bias = cbias[pass * 64 + col];
#pragma unroll
        for (int pt = 0; pt < 4; ++pt) {
          int pxb = pt * 16 + (l >> 4) * 4;
          size_t xfo = ((size_t)(n * 4096 + h * 64 + pxb)) * 128 + pass * 64 + col;
#pragma unroll
          for (int r = 0; r < 4; ++r)
            tr[col][pxb + r] = acc[pt][ct][r] + bias + bf2f(xfb[xfo + (size_t)r * 128]);
        }
      }
    }
    __syncthreads();
#pragma unroll
    for (int q = 0; q < 2; ++q) {
      int it = tid + q * 256;
      int ptl = it >> 7, kt = (it >> 6) & 1, lf = it & 63;
      int dbase = kt * 32 + (lf >> 4) * 8;
      int px = ptl * 16 + (lf & 15);
      unsigned int hw[4], lw[4];
#pragma unroll
      for (int u = 0; u < 4; ++u)
        split2(tr[dbase + 2 * u][px], tr[dbase + 2 * u + 1][px], hw[u], lw[u]);
      size_t base = ((((size_t)n * 256 + h * 4 + ptl) * 2 + pass) * 2 + kt) * 512 + lf * 8;
      *(uint4*)(XSf + base) = make_uint4(hw[0], hw[1], hw[2], hw[3]);
      *(uint4*)(XSl + base) = make_uint4(lw[0], lw[1], lw[2], lw[3]);
    }
    __syncthreads();
  }
}

// K3: Xm[n][d] = mean_p XS (hi+lo)
__global__ __launch_bounds__(256) void k_xmean(const unsigned short* __restrict__ XSf,
                                               const unsigned short* __restrict__ XSl,
                                               float2* __restrict__ Xm) {
  int nd = blockIdx.x;
  int n = nd >> 6, d = nd & 63;
  int kt = d >> 5, hs = (d >> 3) & 3, j = d & 7;
  int tid = threadIdx.x;
  float sr = 0.f, si = 0.f;
  for (int p = tid; p < 4096; p += 256) {
    int ptg = p >> 4, c = p & 15;
    size_t b0 = ((((size_t)n * 256 + ptg) * 2 + 0) * 2 + kt) * 512 + (hs * 16 + c) * 8 + j;
    size_t b1 = ((((size_t)n * 256 + ptg) * 2 + 1) * 2 + kt) * 512 + (hs * 16 + c) * 8 + j;
    sr += bf2f(XSf[b0]) + bf2f(XSl[b0]);
    si += bf2f(XSf[b1]) + bf2f(XSl[b1]);
  }
  __shared__ float r1[256], r2[256];
  r1[tid] = sr; r2[tid] = si;
  __syncthreads();
  for (int s = 128; s > 0; s >>= 1) {
    if (tid < s) { r1[tid] += r1[tid + s]; r2[tid] += r2[tid + s]; }
    __syncthreads();
  }
  if (tid == 0) Xm[nd] = make_float2(r1[0] * (1.f / 4096.f), r2[0] * (1.f / 4096.f));
}

// K4: per (b,t): xmean = Xm @ Ec; fcat = [re,im] @ mix_w + mix_b
__global__ void k_chainA(const float2* __restrict__ Xm, const float* __restrict__ Ere,
                         const float* __restrict__ Eim, const float* __restrict__ mixw,
                         const float* __restrict__ mixb, float2* __restrict__ xmix) {
  int n = blockIdx.x;
  int tid = threadIdx.x;  // 128
  __shared__ float2 xm[64];
  __shared__ float cat[128];
  __shared__ float fc[128];
  if (tid < 64) xm[tid] = Xm[n * 64 + tid];
  __syncthreads();
  if (tid < 64) {
    float ar = 0.f, ai = 0.f;
    for (int d = 0; d < 64; ++d) {
      float2 x = xm[d];
      float er = Ere[d * 64 + tid], ei = Eim[d * 64 + tid];
      ar += x.x * er - x.y * ei;
      ai += x.x * ei + x.y * er;
    }
    cat[tid] = ar; cat[64 + tid] = ai;
  }
  __syncthreads();
  {
    float f = mixb[tid];
    for (int i = 0; i < 128; ++i) f += cat[i] * mixw[i * 128 + tid];
    fc[tid] = f;
  }
  __syncthreads();
  if (tid < 64) xmix[n * 64 + tid] = make_float2(fc[tid], fc[64 + tid]);
}

// K5: flux scan over t
__global__ void k_chainB(const float2* __restrict__ xmix, const float* __restrict__ nu,
                         const float* __restrict__ th, const float* __restrict__ fre,
                         const float* __restrict__ fim, float2* __restrict__ fs) {
  int tid = threadIdx.x;  // 128
  int b = tid >> 6, d = tid & 63;
  float r = expf(-sp_f(nu[d]));
  float dr = r * cosf(th[d]), di = r * sinf(th[d]);
  float yr = 0.f, yi = 0.f, cr = 1.f, ci = 0.f;
  float fr = fre[b * 64 + d], fi = fim[b * 64 + d];
  for (int t = 0; t < 16; ++t) {
    int n = b * 16 + t;
    float ncr = cr * dr - ci * di, nci = cr * di + ci * dr;
    cr = ncr; ci = nci;
    float2 xm = xmix[n * 64 + d];
    float nyr = dr * yr - di * yi + xm.x;
    float nyi = dr * yi + di * yr + xm.y;
    yr = nyr; yi = nyi;
    fs[n * 64 + d] = make_float2(yr + fr * cr - fi * ci, yi + fr * ci + fi * cr);
  }
}

// K6: per (b,t): abo[n][e][8] = {a_r, a_i, bb_r, bb_i, od_r, od_i, 0, 0}
__global__ void k_chainC(const float2* __restrict__ fs, const float* __restrict__ srcw,
                         const float* __restrict__ srcb, const float* __restrict__ gw,
                         const float* __restrict__ gbv, const float* __restrict__ la,
                         const float* __restrict__ lbv, const float* __restrict__ dt,
                         float* __restrict__ abo) {
  int n = blockIdx.x;
  int t = n & 15;
  int tid = threadIdx.x;  // 128
  __shared__ float oc[128];
  __shared__ float sl[128];
  if (tid < 64) { float2 v = fs[n * 64 + tid]; oc[tid] = v.x; oc[64 + tid] = v.y; }
  __syncthreads();
  {
    float s = srcb[tid];
    for (int i = 0; i < 128; ++i) s += oc[i] * srcw[i * 128 + tid];
    sl[tid] = s;
  }
  __syncthreads();
  if (tid < 64) {
    float gv = gbv[tid];
    for (int i = 0; i < 128; ++i) gv += oc[i] * gw[i * 64 + tid];
    float g = 1.f / (1.f + expf(-gv));
    float lr = -sp_f(la[tid]), li = lbv[tid];
    float dtv = dt[t];
    float er = expf(lr * dtv);
    float odr = er * cosf(li * dtv), odi = er * sinf(li * dtv);
    float inv = 1.f / (lr * lr + li * li);
    float nx = odr - 1.f, ny = odi;
    float ofr = (nx * lr + ny * li) * inv, ofi = (ny * lr - nx * li) * inv;
    float s1r = sl[tid] * (1.f - g), s1i = sl[64 + tid] * (1.f - g);
    float* ap = abo + ((size_t)n * 64 + tid) * 8;
    ap[0] = g * ofr;
    ap[1] = g * ofi;
    ap[2] = s1r * ofr - s1i * ofi;
    ap[3] = s1r * ofi + s1i * ofr;
    ap[4] = odr;
    ap[5] = odi;
    ap[6] = 0.f; ap[7] = 0.f;
  }
}

// K7 (fused): encode -> forcing -> scan -> decode -> LN -> on. Split-bf16 precision.
__global__ __launch_bounds__(128) void k_state(
    const unsigned short* __restrict__ XSf, const unsigned short* __restrict__ XSl,
    const unsigned short* __restrict__ efb,
    const float* __restrict__ abo, const float* __restrict__ hre,
    const float* __restrict__ him, const float* __restrict__ ntg,
    const float* __restrict__ ntb, unsigned short* __restrict__ onb) {
  int bq = blockIdx.x;
  int b = bq >> 8, pt = bq & 255;
  int p0 = pt * 16;
  int tid = threadIdx.x;
  int l = tid & 63;
  int eh = __builtin_amdgcn_readfirstlane(tid >> 6);
  int c = l & 15, h4 = l >> 4;

  __shared__ float xpart[2 * 64 * 17];
  __shared__ float ntgl[128], ntbl[128];
  ntgl[tid] = ntg[tid]; ntbl[tid] = ntb[tid];

  const unsigned short* Ehi = efb;
  const unsigned short* Fhi = efb + 8192;
  const unsigned short* Elo = efb + 16384;
  const unsigned short* Flo = efb + 24576;

  bf16x8 erh[2][2], eihh[2][2], erl[2][2], eil[2][2];
#pragma unroll
  for (int es = 0; es < 2; ++es)
#pragma unroll
    for (int kt = 0; kt < 2; ++kt) {
      size_t o = (size_t)(eh * 4096 + es * 1024 + kt * 512 + l * 8);
      erh[es][kt] = *(const bf16x8*)(Ehi + o);
      eihh[es][kt] = *(const bf16x8*)(Ehi + o + 2048);
      erl[es][kt] = *(const bf16x8*)(Elo + o);
      eil[es][kt] = *(const bf16x8*)(Elo + o + 2048);
    }
  bf16x8 frh[4], fih[4], frl[4], fil[4];
#pragma unroll
  for (int ds = 0; ds < 4; ++ds) {
    size_t o = (size_t)(eh * 4096 + ds * 512 + l * 8);
    frh[ds] = *(const bf16x8*)(Fhi + o);
    fih[ds] = *(const bf16x8*)(Fhi + o + 2048);
    frl[ds] = *(const bf16x8*)(Flo + o);
    fil[ds] = *(const bf16x8*)(Flo + o + 2048);
  }

  float yre[2][4], yim[2][4];
#pragma unroll
  for (int es = 0; es < 2; ++es)
#pragma unroll
    for (int r = 0; r < 4; ++r) { yre[es][r] = 0.f; yim[es][r] = 0.f; }

  __syncthreads();

  const f32x4 Z = {0.f, 0.f, 0.f, 0.f};
  for (int t = 0; t < 16; ++t) {
    int n = b * 16 + t;
    bf16x8 xh0[2], xh1[2], xq0[2], xq1[2];
#pragma unroll
    for (int kt = 0; kt < 2; ++kt) {
      size_t b0 = ((((size_t)n * 256 + pt) * 2 + 0) * 2 + kt) * 512 + l * 8;
      size_t b1 = ((((size_t)n * 256 + pt) * 2 + 1) * 2 + kt) * 512 + l * 8;
      xh0[kt] = *(const bf16x8*)(XSf + b0);
      xh1[kt] = *(const bf16x8*)(XSf + b1);
      xq0[kt] = *(const bf16x8*)(XSl + b0);
      xq1[kt] = *(const bf16x8*)(XSl + b1);
    }
    // ---- encode (triple product) + forcing + scan
#pragma unroll
    for (int es = 0; es < 2; ++es) {
      f32x4 a1 = Z, a2 = Z, a3 = Z, a4 = Z;
#pragma unroll
      for (int kt = 0; kt < 2; ++kt) {
        a1 = __builtin_amdgcn_mfma_f32_16x16x32_bf16(erh[es][kt], xh0[kt], a1, 0, 0, 0);
        a1 = __builtin_amdgcn_mfma_f32_16x16x32_bf16(erh[es][kt], xq0[kt], a1, 0, 0, 0);
        a1 = __builtin_amdgcn_mfma_f32_16x16x32_bf16(erl[es][kt], xh0[kt], a1, 0, 0, 0);
        a2 = __builtin_amdgcn_mfma_f32_16x16x32_bf16(eihh[es][kt], xh1[kt], a2, 0, 0, 0);
        a2 = __builtin_amdgcn_mfma_f32_16x16x32_bf16(eihh[es][kt], xq1[kt], a2, 0, 0, 0);
        a2 = __builtin_amdgcn_mfma_f32_16x16x32_bf16(eil[es][kt], xh1[kt], a2, 0, 0, 0);
        a3 = __builtin_amdgcn_mfma_f32_16x16x32_bf16(eihh[es][kt], xh0[kt], a3, 0, 0, 0);
        a3 = __builtin_amdgcn_mfma_f32_16x16x32_bf16(eihh[es][kt], xq0[kt], a3, 0, 0, 0);
        a3 = __builtin_amdgcn_mfma_f32_16x16x32_bf16(eil[es][kt], xh0[kt], a3, 0, 0, 0);
        a4 = __builtin_amdgcn_mfma_f32_16x16x32_bf16(erh[es][kt], xh1[kt], a4, 0, 0, 0);
        a4 = __builtin_amdgcn_mfma_f32_16x16x32_bf16(erh[es][kt], xq1[kt], a4, 0, 0, 0);
        a4 = __builtin_amdgcn_mfma_f32_16x16x32_bf16(erl[es][kt], xh1[kt], a4, 0, 0, 0);
      }
#pragma unroll
      for (int r = 0; r < 4; ++r) {
        int e = eh * 32 + es * 16 + 4 * h4 + r;
        const float* ap = abo + ((size_t)n * 64 + e) * 8;
        float4 cv = *(const float4*)ap;
        float2 ov = *(const float2*)(ap + 4);
        float xr_ = a1[r] - a2[r], xi_ = a3[r] + a4[r];
        float ur = xr_ * cv.x - xi_ * cv.y + cv.z;
        float ui = xr_ * cv.y + xi_ * cv.x + cv.w;
        if (t == 0) {
          size_t ho = ((size_t)(b * 4096 + p0 + c)) * 64 + e;
          float hr = hre[ho], hi = him[ho];
          ur += hr * ov.x - hi * ov.y;
          ui += hr * ov.y + hi * ov.x;
        }
        float nyr = ov.x * yre[es][r] - ov.y * yim[es][r] + ur;
        float nyi = ov.x * yim[es][r] + ov.y * yre[es][r] + ui;
        yre[es][r] = nyr; yim[es][r] = nyi;
      }
    }
    // ---- y -> split bf16 hi/lo B-fragments, in-register shfl transpose.
    unsigned int hr_[2][2], lr_[2][2], hi_[2][2], li_[2][2];
#pragma unroll
    for (int es = 0; es < 2; ++es) {
      split2(yre[es][0], yre[es][1], hr_[es][0], lr_[es][0]);
      split2(yre[es][2], yre[es][3], hr_[es][1], lr_[es][1]);
      split2(yim[es][0], yim[es][1], hi_[es][0], li_[es][0]);
      split2(yim[es][2], yim[es][3], hi_[es][1], li_[es][1]);
    }
    int base_src = c + 16 * (2 * (h4 & 1));
    int hsel = h4 >> 1;
    u32x4 urh, uih, url, uil;
#pragma unroll
    for (int jj = 0; jj < 4; ++jj) {
      int src = base_src + 16 * (jj >> 1);
      unsigned int t0, t1;
      t0 = (unsigned int)__shfl((int)hr_[0][jj & 1], src);
      t1 = (unsigned int)__shfl((int)hr_[1][jj & 1], src);
      urh[jj] = hsel ? t1 : t0;
      t0 = (unsigned int)__shfl((int)hi_[0][jj & 1], src);
      t1 = (unsigned int)__shfl((int)hi_[1][jj & 1], src);
      uih[jj] = hsel ? t1 : t0;
      t0 = (unsigned int)__shfl((int)lr_[0][jj & 1], src);
      t1 = (unsigned int)__shfl((int)lr_[1][jj & 1], src);
      url[jj] = hsel ? t1 : t0;
      t0 = (unsigned int)__shfl((int)li_[0][jj & 1], src);
      t1 = (unsigned int)__shfl((int)li_[1][jj & 1], src);
      uil[jj] = hsel ? t1 : t0;
    }
    bf16x8 ybrh = __builtin_bit_cast(bf16x8, urh);
    bf16x8 ybih = __builtin_bit_cast(bf16x8, uih);
    bf16x8 ybrl = __builtin_bit_cast(bf16x8, url);
    bf16x8 ybil = __builtin_bit_cast(bf16x8, uil);
    // ---- decode (triple product, partial over this wave's e-half)
    float v[2][4][4];
#pragma unroll
    for (int ds = 0; ds < 4; ++ds) {
      f32x4 d1 = Z, d2 = Z, d3 = Z, d4 = Z;
      d1 = __builtin_amdgcn_mfma_f32_16x16x32_bf16(frh[ds], ybrh, d1, 0, 0, 0);
      d1 = __builtin_amdgcn_mfma_f32_16x16x32_bf16(frh[ds], ybrl, d1, 0, 0, 0);
      d1 = __builtin_amdgcn_mfma_f32_16x16x32_bf16(frl[ds], ybrh, d1, 0, 0, 0);
      d2 = __builtin_amdgcn_mfma_f32_16x16x32_bf16(fih[ds], ybih, d2, 0, 0, 0);
      d2 = __builtin_amdgcn_mfma_f32_16x16x32_bf16(fih[ds], ybil, d2, 0, 0, 0);
      d2 = __builtin_amdgcn_mfma_f32_16x16x32_bf16(fil[ds], ybih, d2, 0, 0, 0);
      d3 = __builtin_amdgcn_mfma_f32_16x16x32_bf16(fih[ds], ybrh, d3, 0, 0, 0);
      d3 = __builtin_amdgcn_mfma_f32_16x16x32_bf16(fih[ds], ybrl, d3, 0, 0, 0);
      d3 = __builtin_amdgcn_mfma_f32_16x16x32_bf16(fil[ds], ybrh, d3, 0, 0, 0);
      d4 = __builtin_amdgcn_mfma_f32_16x16x32_bf16(frh[ds], ybih, d4, 0, 0, 0);
      d4 = __builtin_amdgcn_mfma_f32_16x16x32_bf16(frh[ds], ybil, d4, 0, 0, 0);
      d4 = __builtin_amdgcn_mfma_f32_16x16x32_bf16(frl[ds], ybih, d4, 0, 0, 0);
#pragma unroll
      for (int r = 0; r < 4; ++r) {
        v[0][ds][r] = d1[r] - d2[r];
        v[1][ds][r] = d3[r] + d4[r];
      }
    }
    bool own = (eh == (t & 1));
    if (!own) {
#pragma unroll
      for (int p = 0; p < 2; ++p)
#pragma unroll
        for (int ds = 0; ds < 4; ++ds)
#pragma unroll
          for (int r = 0; r < 4; ++r)
            xpart[(p * 64 + ds * 16 + 4 * h4 + r) * 17 + c] = v[p][ds][r];
    }
    __syncthreads();
    if (own) {
      float s = 0.f, s2 = 0.f;
#pragma unroll
      for (int p = 0; p < 2; ++p)
#pragma unroll
        for (int ds = 0; ds < 4; ++ds)
#pragma unroll
          for (int r = 0; r < 4; ++r) {
            float q2 = v[p][ds][r] + xpart[(p * 64 + ds * 16 + 4 * h4 + r) * 17 + c];
            v[p][ds][r] = q2;
            s += q2; s2 += q2 * q2;
          }
      s += __shfl_xor(s, 16); s += __shfl_xor(s, 32);
      s2 += __shfl_xor(s2, 16); s2 += __shfl_xor(s2, 32);
      float mu = s * (1.f / 128.f);
      float rsv = rsqrtf(s2 * (1.f / 128.f) - mu * mu + 1e-5f);
      size_t ob = ((size_t)(n * 4096 + p0 + c)) * 128;
#pragma unroll
      for (int p = 0; p < 2; ++p)
#pragma unroll
        for (int ds = 0; ds < 4; ++ds) {
          int ch = p * 64 + ds * 16 + 4 * h4;
          float l0 = (v[p][ds][0] - mu) * rsv * ntgl[ch + 0] + ntbl[ch + 0];
          float l1 = (v[p][ds][1] - mu) * rsv * ntgl[ch + 1] + ntbl[ch + 1];
          float l2 = (v[p][ds][2] - mu) * rsv * ntgl[ch + 2] + ntbl[ch + 2];
          float l3 = (v[p][ds][3] - mu) * rsv * ntgl[ch + 3] + ntbl[ch + 3];
          *(unsigned int*)&onb[ob + ch] = cvtpk(l0, l1);
          *(unsigned int*)&onb[ob + ch + 2] = cvtpk(l2, l3);
        }
    }
    __syncthreads();
  }
}

// K10: MoE via swapped-operand 32x32 MFMA; residual from XS hi+lo.
// Single e-loop (macc[4][16]) + 2-phase epilogue (LDS 34304). No occupancy attrs.
__global__ __launch_bounds__(256) void k_moe2(
    const unsigned short* __restrict__ onb, const unsigned short* __restrict__ w1tp,
    const unsigned short* __restrict__ w2p32, const unsigned short* __restrict__ rwp,
    const float* __restrict__ rb, const float* __restrict__ b1, const float* __restrict__ b2,
    const unsigned short* __restrict__ XSf, const unsigned short* __restrict__ XSl,
    float* __restrict__ out) {
  int n = blockIdx.x >> 6, ptile = blockIdx.x & 63;
  int p0 = ptile * 64;
  __shared__ __align__(16) short At[64 * 128];   // 16KB
  __shared__ __align__(16) float buf[4160];      // 16.6KB: biases -> red -> fin
  __shared__ float pr[64][4];
  int tid = threadIdx.x;
  int l = tid & 63;
  int w = __builtin_amdgcn_readfirstlane(tid >> 6);
  int h = l >> 5, s = l & 31;
  float* b1l = buf;
  float* b2l = buf + 1024;

  for (int i = tid; i < 1024; i += 256) b1l[i] = b1[i];
  for (int i = tid; i < 512; i += 256) b2l[i] = b2[i];

  {
    const char* gsrc = (const char*)onb + ((size_t)n * 4096 + p0) * 256;
#pragma unroll
    for (int it = 0; it < 4; ++it) {
      int ch = tid + it * 256;
      int row = ch >> 4, cb = (ch & 15) * 16;
      float4 v = *(const float4*)(gsrc + (size_t)row * 256 + cb);
      int off = (row * 256 + cb) ^ ((row & 7) << 4);
      *(float4*)((char*)At + off) = v;
    }
  }
  __syncthreads();

  {
    f32x4 acc = {0.f, 0.f, 0.f, 0.f};
#pragma unroll
    for (int kt = 0; kt < 4; ++kt) {
      int row = w * 16 + (l & 15);
      int off = (row * 256 + kt * 64 + (l >> 4) * 16) ^ ((row & 7) << 4);
      bf16x8 aa = *(const bf16x8*)((const char*)At + off);
      bf16x8 bb = *(const bf16x8*)(rwp + ((size_t)kt * 64 + l) * 8);
      acc = __builtin_amdgcn_mfma_f32_16x16x32_bf16(aa, bb, acc, 0, 0, 0);
    }
    int e = l & 15;
    float rbv = e < 4 ? rb[e] : 0.f;
#pragma unroll
    for (int r = 0; r < 4; ++r) {
      float lg = acc[r] + rbv;
      float m = fmaxf(lg, __shfl_xor(lg, 1));
      m = fmaxf(m, __shfl_xor(m, 2));
      float ex = __expf(lg - m);
      float sm = ex + __shfl_xor(ex, 1);
      sm += __shfl_xor(sm, 2);
      float p = ex * __builtin_amdgcn_rcpf(sm);
      if (e < 4) pr[w * 16 + (l >> 4) * 4 + r][e] = p;
    }
  }
  __syncthreads();

  int pw = w & 1, mh = w >> 1;
  int rowb = pw * 32 + s;
  int swz = (rowb & 7) << 4;

  float macc[4][16];
#pragma unroll
  for (int ct = 0; ct < 4; ++ct)
#pragma unroll
    for (int r = 0; r < 16; ++r) macc[ct][r] = 0.f;

  const f32x16 Z16 = {0.f, 0.f, 0.f, 0.f, 0.f, 0.f, 0.f, 0.f,
                      0.f, 0.f, 0.f, 0.f, 0.f, 0.f, 0.f, 0.f};

  for (int e = 0; e < 4; ++e) {
    u32x4 af[8];
#pragma unroll
    for (int mt = 0; mt < 4; ++mt) {
      f32x16 acc = Z16;
#pragma unroll
      for (int kt = 0; kt < 8; ++kt) {
        bf16x8 a = *(const bf16x8*)(
            w1tp + ((((size_t)e * 8 + (mh * 4 + mt)) * 8 + kt) * 64 + l) * 8);
        int off = (rowb * 256 + kt * 32 + h * 16) ^ swz;
        bf16x8 b = *(const bf16x8*)((const char*)At + off);
        acc = __builtin_amdgcn_mfma_f32_32x32x16_bf16(a, b, acc, 0, 0, 0);
      }
      unsigned int hpk[8];
#pragma unroll
      for (int i2 = 0; i2 < 8; ++i2) {
        int r0 = 2 * i2;
        int m0 = mh * 128 + mt * 32 + (r0 & 3) + 8 * (r0 >> 2) + 4 * h;
        float2 bv = *(const float2*)&b1l[e * 256 + m0];
        hpk[i2] = cvtpk(gelu_f(acc[r0] + bv.x), gelu_f(acc[r0 + 1] + bv.y));
      }
#pragma unroll
      for (int hf = 0; hf < 2; ++hf) {
        unsigned int pA = hpk[4 * hf + 0], pB = hpk[4 * hf + 1];
        unsigned int pC = hpk[4 * hf + 2], pD = hpk[4 * hf + 3];
        unsigned int Z0 = h ? pC : pA, Z1 = h ? pD : pB;
        unsigned int S0 = h ? pA : pC, S1 = h ? pB : pD;
        unsigned int Ss0 = (unsigned int)__shfl_xor((int)S0, 32);
        unsigned int Ss1 = (unsigned int)__shfl_xor((int)S1, 32);
        u32x4 fr2;
        fr2.x = h ? Ss0 : Z0;
        fr2.y = h ? Ss1 : Z1;
        fr2.z = h ? Z0 : Ss0;
        fr2.w = h ? Z1 : Ss1;
        af[mt * 2 + hf] = fr2;
      }
    }
    float prv[16];
#pragma unroll
    for (int r = 0; r < 16; ++r) {
      int px = pw * 32 + (r & 3) + 8 * (r >> 2) + 4 * h;
      prv[r] = pr[px][e];
    }
#pragma unroll
    for (int ct = 0; ct < 4; ++ct) {
      f32x16 acc = Z16;
#pragma unroll
      for (int kt = 0; kt < 8; ++kt) {
        bf16x8 bf = *(const bf16x8*)(
            w2p32 + ((((size_t)e * 16 + (mh * 8 + kt)) * 4 + ct) * 64 + l) * 8);
        bf16x8 a = __builtin_bit_cast(bf16x8, af[kt]);
        acc = __builtin_amdgcn_mfma_f32_32x32x16_bf16(a, bf, acc, 0, 0, 0);
      }
      float b2v = mh ? 0.f : b2l[e * 128 + ct * 32 + s];
#pragma unroll
      for (int r = 0; r < 16; ++r) macc[ct][r] += (acc[r] + b2v) * prv[r];
    }
  }

  // ---- two phases: (reduce ct-pair) -> fin (64 ch) -> out (64 ch)
#pragma unroll
  for (int ph = 0; ph < 2; ++ph) {
    int ct0 = ph * 2;
    __syncthreads();
    if (mh == 1) {
#pragma unroll
      for (int g = 0; g < 8; ++g) {
        int ct = ct0 + (g >> 2), q = (g & 3) * 4;
        float4 v = make_float4(macc[ct][q], macc[ct][q + 1], macc[ct][q + 2], macc[ct][q + 3]);
        *(float4*)&buf[((g * 2 + pw) * 64 + l) * 4] = v;
      }
    }
    __syncthreads();
    if (mh == 0) {
#pragma unroll
      for (int g = 0; g < 8; ++g) {
        float4 v = *(const float4*)&buf[((g * 2 + pw) * 64 + l) * 4];
        int ct = ct0 + (g >> 2), q = (g & 3) * 4;
        macc[ct][q] += v.x; macc[ct][q + 1] += v.y;
        macc[ct][q + 2] += v.z; macc[ct][q + 3] += v.w;
      }
    }
    __syncthreads();
    if (mh == 0) {
#pragma unroll
      for (int cti = 0; cti < 2; ++cti) {
        int ct = ct0 + cti;
        int cc = ct * 32 + s;
        int cl = cc - ph * 64;
#pragma unroll
        for (int r = 0; r < 16; ++r) {
          int px = pw * 32 + (r & 3) + 8 * (r >> 2) + 4 * h;
          int aoff = (px * 256 + cc * 2) ^ ((px & 7) << 4);
          float onv = bf2f(((unsigned short*)At)[aoff >> 1]);
          buf[px * 65 + cl] = macc[ct][r] + onv;
        }
      }
    }
    __syncthreads();
    for (int idx = tid; idx < 64 * 64; idx += 256) {
      int px = idx & 63, cl = idx >> 6;
      int p = p0 + px;
      size_t el = ((((size_t)n * 256 + (p >> 4)) * 2 + ph) * 2 + (cl >> 5)) * 512
                + (((cl >> 3) & 3) * 16 + (p & 15)) * 8 + (cl & 7);
      float resid = bf2f(XSf[el]) + bf2f(XSl[el]);
      out[((size_t)n * 128 + ph * 64 + cl) * 4096 + p0 + px] = resid + buf[px * 65 + cl];
    }
  }
}

extern "C" void kernel_launch(void* const* d_in, const int* in_sizes, int n_in,
                              void* d_out, int out_size, void* d_ws, size_t ws_size,
                              hipStream_t stream) {
  const float* xre = (const float*)d_in[0];
  const float* xim = (const float*)d_in[1];
  const float* hre = (const float*)d_in[2];
  const float* him = (const float*)d_in[3];
  const float* dt = (const float*)d_in[4];
  const float* fre = (const float*)d_in[5];
  const float* fim = (const float*)d_in[6];
  const float* nsg = (const float*)d_in[7];
  const float* nsb = (const float*)d_in[8];
  const float* cw = (const float*)d_in[9];
  const float* cb = (const float*)d_in[10];
  const float* Ere = (const float*)d_in[11];
  const float* Eim = (const float*)d_in[12];
  const float* Fre = (const float*)d_in[13];
  const float* Fim = (const float*)d_in[14];
  const float* mixw = (const float*)d_in[15];
  const float* mixb = (const float*)d_in[16];
  const float* nu = (const float*)d_in[17];
  const float* th = (const float*)d_in[18];
  const float* srcw = (const float*)d_in[19];
  const float* srcb = (const float*)d_in[20];
  const float* gw = (const float*)d_in[21];
  const float* gbv = (const float*)d_in[22];
  const float* la = (const float*)d_in[23];
  const float* lb = (const float*)d_in[24];
  const float* ntg = (const float*)d_in[25];
  const float* ntb = (const float*)d_in[26];
  const float* rw = (const float*)d_in[27];
  const float* rb = (const float*)d_in[28];
  const float* w1 = (const float*)d_in[29];
  const float* b1 = (const float*)d_in[30];
  const float* w2 = (const float*)d_in[31];
  const float* b2 = (const float*)d_in[32];

  unsigned short* XSf = (unsigned short*)d_ws;
  unsigned short* XSl = XSf + 16777216;
  unsigned short* onb16 = XSl + 16777216;
  unsigned short* wcv = onb16 + 16777216;        // 147456
  unsigned short* w1tp = wcv + 147456;           // 131072
  unsigned short* w2p32 = w1tp + 131072;         // 131072
  unsigned short* rwp = w2p32 + 131072;          // 2048
  unsigned short* efb = rwp + 2048;              // 32768 (hi 16384 + lo 16384)
  float* smf = (float*)(efb + 32768);
  float* abo = smf;                              // 32*64*8 = 16384 f32
  float2* Xm = (float2*)(abo + 16384);           // 2048 float2
  float2* xmix = Xm + TN * 64;
  float2* fsb = xmix + TN * 64;

  float* out = (float*)d_out;
  unsigned short* xnb = (unsigned short*)d_out;        // bf16, dead after k_conv
  unsigned short* xfb = xnb + 16777216;                // bf16 raw x, dead after k_conv

  hipLaunchKernelGGL(k_repc, dim3(576), dim3(256), 0, stream, cw, wcv);
  hipLaunchKernelGGL(k_repw, dim3(1033), dim3(256), 0, stream, w1, w2, rw, w1tp, w2p32, rwp);
  hipLaunchKernelGGL(k_repEF, dim3(128), dim3(256), 0, stream, Ere, Eim, Fre, Fim, efb);
  hipLaunchKernelGGL(k_ln_in, dim3(TN * 64), dim3(256), 0, stream, xre, xim, nsg, nsb, xnb, xfb);
  hipLaunchKernelGGL(k_conv, dim3(TN * 64), dim3(256), 0, stream, xnb, wcv, cb, xfb, XSf, XSl);
  hipLaunchKernelGGL(k_xmean, dim3(TN * 64), dim3(256), 0, stream, XSf, XSl, Xm);
  hipLaunchKernelGGL(k_chainA, dim3(TN), dim3(128), 0, stream, Xm, Ere, Eim, mixw, mixb, xmix);
  hipLaunchKernelGGL(k_chainB, dim3(1), dim3(128), 0, stream, xmix, nu, th, fre, fim, fsb);
  hipLaunchKernelGGL(k_chainC, dim3(TN), dim3(128), 0, stream, fsb, srcw, srcb, gw, gbv, la, lb,
                     dt, abo);
  hipLaunchKernelGGL(k_state, dim3(512), dim3(128), 0, stream, XSf, XSl, efb, abo, hre, him,
                     ntg, ntb, onb16);
  hipLaunchKernelGGL(k_moe2, dim3(TN * 64), dim3(256), 0, stream, onb16, w1tp, w2p32, rwp, rb,
                     b1, b2, XSf, XSl, out);
  (void)in_sizes; (void)n_in; (void)out_size; (void)ws_size;
}